// Round 8
// baseline (1079.712 us; speedup 1.0000x reference)
//
#include <hip/hip_runtime.h>
#include <hip/hip_bf16.h>
#include <math.h>

namespace {
constexpr int CDIM   = 128;
constexpr int KCODES = 1024;
constexpr int HWSZ   = 4096;   // 64*64
constexpr int BATCH  = 16;
constexpr int NPOS   = BATCH * HWSZ;            // 65536
constexpr size_t QELEMS   = (size_t)BATCH * CDIM * HWSZ;   // 8388608
constexpr size_t IDX_OFF  = QELEMS;                        // float32 elements
constexpr size_t LOSS_OFF = IDX_OFF + (size_t)NPOS;        // 8454144
constexpr size_t PERP_OFF = LOSS_OFF + 1;
// d_ws float-element offsets
constexpr int WS_C2   = 0;      // [0,1024)   float ||c_k||^2 (numpy-bit-exact)
constexpr int WS_HIST = 1024;   // [1024,2048) uint  usage counts
constexpr int WS_LOSS = 2048;   // [2048]     float sum ||z-q||^2
constexpr float INV_TOTAL = 1.0f / (float)QELEMS;
constexpr float INV_NPOS  = 1.0f / (float)NPOS;
}

// Bit-exact replica of numpy pairwise_sum for n=128 contiguous float32 applied
// to elementwise squares: 8 accumulator chains (stride 8), sequential within a
// chain, combined ((r0+r1)+(r2+r3))+((r4+r5)+(r6+r7)). __f*_rn forbids fma
// contraction (numpy multiplies into a temp, then adds — never fused).
__device__ __forceinline__ float np_sumsq_128(const float* v) {
    float r[8];
    #pragma unroll
    for (int j = 0; j < 8; ++j) r[j] = __fmul_rn(v[j], v[j]);
    #pragma unroll
    for (int i = 8; i < 128; i += 8) {
        #pragma unroll
        for (int j = 0; j < 8; ++j)
            r[j] = __fadd_rn(r[j], __fmul_rn(v[i + j], v[i + j]));
    }
    const float s01 = __fadd_rn(r[0], r[1]);
    const float s23 = __fadd_rn(r[2], r[3]);
    const float s45 = __fadd_rn(r[4], r[5]);
    const float s67 = __fadd_rn(r[6], r[7]);
    return __fadd_rn(__fadd_rn(s01, s23), __fadd_rn(s45, s67));
}

// ---- pass 0: codebook norms (numpy-bit-exact) + zero accumulators ----------
__global__ __launch_bounds__(256) void vq_prep(const float* __restrict__ cb,
                                               float* __restrict__ ws) {
    const int k = blockIdx.x * 256 + threadIdx.x;   // 0..1023
    const float* row = cb + (size_t)k * CDIM;
    float rr[CDIM];
    #pragma unroll
    for (int c = 0; c < CDIM; ++c) rr[c] = row[c];
    ws[WS_C2 + k] = np_sumsq_128(rr);
    ((unsigned int*)ws)[WS_HIST + k] = 0u;
    if (k == 0) ws[WS_LOSS] = 0.0f;
}

// ---- pass 1: argmin. 1 wave/block, 64 pos; z in LDS [c][pos] (per-use
// conflict-free b32 reads, nothing long-lived for the allocator to remat);
// cb via wave-uniform float4 global loads (16-code pass = 8KB, L1-resident).
// Live set: acc[16] + ~20 transients — sized to the ~88-VGPR behavior
// observed in r4-r7. Per cq: 64 FMA (128cyc) vs LDS 23cyc*4w, VMEM 64cyc.
// Numerics identical to round-4 passing chain.
__global__ __launch_bounds__(64, 1) void vq_main(const float* __restrict__ z,
                                                 const float* __restrict__ cb,
                                                 float* __restrict__ ws,
                                                 float* __restrict__ out) {
    __shared__ __align__(16) float zt[64 * CDIM];     // [c][pos] 32 KB
    __shared__ unsigned int lhist[KCODES];            // 4 KB

    const int tid = threadIdx.x;       // 0..63 == lane
    const int n0  = blockIdx.x * 64;
    const int b   = n0 >> 12;
    const int hw0 = n0 & (HWSZ - 1);
    const int n   = n0 + tid;

    // stage z tile [c][64 pos] (float4 over pos, coalesced)
    const float4* zsrc4 = (const float4*)(z + (size_t)b * CDIM * HWSZ + hw0);
    float4* zt4 = (float4*)zt;
    #pragma unroll
    for (int i = 0; i < 32; ++i) {
        const int idx = i * 64 + tid;  // 0..2047
        const int c = idx >> 4, q = idx & 15;
        zt4[idx] = zsrc4[(size_t)c * (HWSZ / 4) + q];
    }
    for (int i = tid; i < KCODES; i += 64) lhist[i] = 0u;
    __syncthreads();

    // z2 bit-identical to np.sum(z_flat*z_flat, axis=1)
    float z2;
    {
        float rr[CDIM];
        #pragma unroll
        for (int c = 0; c < CDIM; ++c) rr[c] = zt[c * 64 + tid];
        z2 = np_sumsq_128(rr);
    }

    const float* c2g = ws + WS_C2;
    float best_d = INFINITY;
    int   best_k = 0;

    for (int pass = 0; pass < KCODES / 16; ++pass) {
        const float4* cbp = (const float4*)cb + (size_t)(pass * 16) * (CDIM / 4);
        float acc[16];
        #pragma unroll
        for (int j = 0; j < 16; ++j) acc[j] = 0.0f;

        #pragma unroll 2
        for (int cq = 0; cq < CDIM / 4; ++cq) {
            const float za = zt[(cq * 4 + 0) * 64 + tid];
            const float zb = zt[(cq * 4 + 1) * 64 + tid];
            const float zc = zt[(cq * 4 + 2) * 64 + tid];
            const float zd = zt[(cq * 4 + 3) * 64 + tid];
            #pragma unroll
            for (int j = 0; j < 16; ++j) {
                const float4 cv = cbp[(size_t)j * (CDIM / 4) + cq];
                // ascending-c sequential chain per (pos,code) — round-4 order
                acc[j] = fmaf(cv.x, za, acc[j]);
                acc[j] = fmaf(cv.y, zb, acc[j]);
                acc[j] = fmaf(cv.z, zc, acc[j]);
                acc[j] = fmaf(cv.w, zd, acc[j]);
            }
        }

        const int k0 = pass * 16;
        #pragma unroll
        for (int j = 0; j < 16; ++j) {
            // d = fl(fl(z2 - 2*zc) + c2); fmaf(-2,a,z2) == fl(z2-2a) (2a exact)
            const float d = __fadd_rn(fmaf(-2.0f, acc[j], z2), c2g[k0 + j]);
            // strict < ascending k == np.argmin first-index tie-break
            if (d < best_d) { best_d = d; best_k = k0 + j; }
        }
    }

    // index output (fp32)
    out[IDX_OFF + (size_t)n] = (float)best_k;

    // quantized output: fp32 gather of winning codebook row
    const float4* q4 = (const float4*)(cb + (size_t)best_k * CDIM);
    float* op = out + (size_t)b * CDIM * HWSZ + hw0 + tid;
    #pragma unroll
    for (int q = 0; q < CDIM / 4; ++q) {
        const float4 v = q4[q];
        op[(size_t)(4 * q + 0) * HWSZ] = v.x;
        op[(size_t)(4 * q + 1) * HWSZ] = v.y;
        op[(size_t)(4 * q + 2) * HWSZ] = v.z;
        op[(size_t)(4 * q + 3) * HWSZ] = v.w;
    }

    // histogram + loss (best_d == fl(||z-q||^2), ~128 magnitude, 2% slack)
    atomicAdd(&lhist[best_k], 1u);
    float sum = best_d;
    #pragma unroll
    for (int m = 1; m < 64; m <<= 1) sum += __shfl_xor(sum, m);
    if (tid == 0) atomicAdd(&ws[WS_LOSS], sum);
    __syncthreads();

    unsigned int* ghist = (unsigned int*)ws + WS_HIST;
    for (int i = tid; i < KCODES; i += 64) {
        const unsigned int v = lhist[i];
        if (v) atomicAdd(&ghist[i], v);
    }
}

// ---- pass 2: scalars --------------------------------------------------------
__global__ __launch_bounds__(1024) void vq_final(const float* __restrict__ ws,
                                                 float* __restrict__ out) {
    __shared__ float red[1024];
    const int t = threadIdx.x;
    const unsigned int* hist = (const unsigned int*)ws + WS_HIST;
    const float p = (float)hist[t] * INV_NPOS;
    red[t] = p * logf(p + 1e-10f);
    __syncthreads();
    for (int s = 512; s > 0; s >>= 1) {
        if (t < s) red[t] += red[t + s];
        __syncthreads();
    }
    if (t == 0) {
        out[LOSS_OFF] = 1.25f * (ws[WS_LOSS] * INV_TOTAL);   // cb + 0.25*commit
        out[PERP_OFF] = expf(-red[0]);
    }
}

extern "C" void kernel_launch(void* const* d_in, const int* in_sizes, int n_in,
                              void* d_out, int out_size, void* d_ws, size_t ws_size,
                              hipStream_t stream) {
    const float* z  = (const float*)d_in[0];
    const float* cb = (const float*)d_in[1];
    float* out = (float*)d_out;
    float* ws  = (float*)d_ws;

    vq_prep <<<KCODES / 256, 256, 0, stream>>>(cb, ws);
    vq_main <<<NPOS / 64,     64, 0, stream>>>(z, cb, ws, out);
    vq_final<<<1,           1024, 0, stream>>>(ws, out);
}

// Round 9
// 992.915 us; speedup vs baseline: 1.0874x; 1.0874x over previous
//
#include <hip/hip_runtime.h>
#include <hip/hip_bf16.h>
#include <math.h>

namespace {
constexpr int CDIM   = 128;
constexpr int KCODES = 1024;
constexpr int HWSZ   = 4096;   // 64*64
constexpr int BATCH  = 16;
constexpr int NPOS   = BATCH * HWSZ;            // 65536
constexpr int POSB   = 32;                      // positions per block
constexpr size_t QELEMS   = (size_t)BATCH * CDIM * HWSZ;   // 8388608
constexpr size_t IDX_OFF  = QELEMS;                        // float32 elements
constexpr size_t LOSS_OFF = IDX_OFF + (size_t)NPOS;        // 8454144
constexpr size_t PERP_OFF = LOSS_OFF + 1;
// d_ws float-element offsets
constexpr int WS_C2   = 0;      // [0,1024)   float ||c_k||^2 (numpy-bit-exact)
constexpr int WS_HIST = 1024;   // [1024,2048) uint  usage counts
constexpr int WS_LOSS = 2048;   // [2048]     float sum ||z-q||^2
constexpr float INV_TOTAL = 1.0f / (float)QELEMS;
constexpr float INV_NPOS  = 1.0f / (float)NPOS;
}

// Bit-exact replica of numpy pairwise_sum for n=128 contiguous float32 applied
// to elementwise squares: 8 accumulator chains (stride 8), sequential within a
// chain, combined ((r0+r1)+(r2+r3))+((r4+r5)+(r6+r7)). __f*_rn forbids fma
// contraction (numpy multiplies into a temp, then adds — never fused).
__device__ __forceinline__ float np_sumsq_128(const float* v) {
    float r[8];
    #pragma unroll
    for (int j = 0; j < 8; ++j) r[j] = __fmul_rn(v[j], v[j]);
    #pragma unroll
    for (int i = 8; i < 128; i += 8) {
        #pragma unroll
        for (int j = 0; j < 8; ++j)
            r[j] = __fadd_rn(r[j], __fmul_rn(v[i + j], v[i + j]));
    }
    const float s01 = __fadd_rn(r[0], r[1]);
    const float s23 = __fadd_rn(r[2], r[3]);
    const float s45 = __fadd_rn(r[4], r[5]);
    const float s67 = __fadd_rn(r[6], r[7]);
    return __fadd_rn(__fadd_rn(s01, s23), __fadd_rn(s45, s67));
}

// ---- pass 0: codebook norms (numpy-bit-exact) + zero accumulators ----------
__global__ __launch_bounds__(256) void vq_prep(const float* __restrict__ cb,
                                               float* __restrict__ ws) {
    const int k = blockIdx.x * 256 + threadIdx.x;   // 0..1023
    const float* row = cb + (size_t)k * CDIM;
    float rr[CDIM];
    #pragma unroll
    for (int c = 0; c < CDIM; ++c) rr[c] = row[c];
    ws[WS_C2 + k] = np_sumsq_128(rr);
    ((unsigned int*)ws)[WS_HIST + k] = 0u;
    if (k == 0) ws[WS_LOSS] = 0.0f;
}

// ---- pass 1: argmin. 1 wave/block, 32 positions x 2 code-halves.
// z in LDS [c][pos] (conflict-free b32, broadcast across halves); cb via
// per-half global float4 loads with EXPLICIT register double-buffer (prefetch
// cq+1 during cq's FMAs). LDS 18.6KB -> 8 blocks/CU = 2 waves/SIMD (TLP covers
// residual latency). Live set ~90 VGPR — sized to the allocator behavior seen
// in r4-r8. Numerics identical to round-4 passing chain.
__global__ __launch_bounds__(64, 2) void vq_main(const float* __restrict__ z,
                                                 const float* __restrict__ cb,
                                                 float* __restrict__ ws,
                                                 float* __restrict__ out) {
    __shared__ __align__(16) float zt[CDIM * POSB];   // [c][pos] 16 KB
    __shared__ unsigned int lhist2[KCODES / 2];       // packed u16 pairs, 2 KB
    __shared__ float z2s[POSB];

    const int tid  = threadIdx.x;       // 0..63
    const int pos  = tid & 31;
    const int half = tid >> 5;          // 0/1 -> codes 8h..8h+8 of each pass
    const int n0   = blockIdx.x * POSB;
    const int b    = n0 >> 12;
    const int hw0  = n0 & (HWSZ - 1);

    // stage z tile [c][32 pos] (float4 over pos, coalesced)
    const float4* zsrc4 = (const float4*)(z + (size_t)b * CDIM * HWSZ + hw0);
    float4* zt4 = (float4*)zt;
    #pragma unroll
    for (int i = 0; i < 16; ++i) {
        const int idx = i * 64 + tid;   // 0..1023
        const int c = idx >> 3, q = idx & 7;
        zt4[idx] = zsrc4[(size_t)c * (HWSZ / 4) + q];
    }
    for (int i = tid; i < KCODES / 2; i += 64) lhist2[i] = 0u;
    __syncthreads();

    // z2 per position (numpy pairwise chain, bit-exact), lanes 0..31
    if (tid < POSB) {
        float rr[CDIM];
        #pragma unroll
        for (int c = 0; c < CDIM; ++c) rr[c] = zt[c * POSB + tid];
        z2s[tid] = np_sumsq_128(rr);
    }
    __syncthreads();
    const float z2 = z2s[pos];

    const float* c2g = ws + WS_C2;
    float best_d = INFINITY;
    int   best_k = 0;
    const int coff = half * 8;

    for (int pass = 0; pass < KCODES / 16; ++pass) {
        // thread's 8 code rows for this pass, as float4 [code][cq]
        const float4* cbp = (const float4*)cb
                          + (size_t)(pass * 16 + coff) * (CDIM / 4);
        float4 buf[8];
        #pragma unroll
        for (int j = 0; j < 8; ++j) buf[j] = cbp[(size_t)j * 32];
        float acc[8];
        #pragma unroll
        for (int j = 0; j < 8; ++j) acc[j] = 0.0f;

        #pragma unroll
        for (int cq = 0; cq < 32; ++cq) {
            float4 nxt[8];
            if (cq < 31) {
                #pragma unroll
                for (int j = 0; j < 8; ++j) nxt[j] = cbp[(size_t)j * 32 + cq + 1];
            }
            const float za = zt[(cq * 4 + 0) * POSB + pos];
            const float zb = zt[(cq * 4 + 1) * POSB + pos];
            const float zc = zt[(cq * 4 + 2) * POSB + pos];
            const float zd = zt[(cq * 4 + 3) * POSB + pos];
            #pragma unroll
            for (int j = 0; j < 8; ++j) {
                // ascending-c sequential chain per (pos,code) — round-4 order
                acc[j] = fmaf(buf[j].x, za, acc[j]);
                acc[j] = fmaf(buf[j].y, zb, acc[j]);
                acc[j] = fmaf(buf[j].z, zc, acc[j]);
                acc[j] = fmaf(buf[j].w, zd, acc[j]);
            }
            if (cq < 31) {
                #pragma unroll
                for (int j = 0; j < 8; ++j) buf[j] = nxt[j];
            }
        }

        const int k0 = pass * 16 + coff;
        #pragma unroll
        for (int j = 0; j < 8; ++j) {
            // d = fl(fl(z2 - 2*zc) + c2); fmaf(-2,a,z2) == fl(z2-2a) (2a exact)
            const float d = __fadd_rn(fmaf(-2.0f, acc[j], z2), c2g[k0 + j]);
            // strict < ascending k == np.argmin first-index tie-break
            if (d < best_d) { best_d = d; best_k = k0 + j; }
        }
    }

    // combine the two code-halves (same pos), order-free tie predicate
    {
        const float od = __shfl_xor(best_d, 32);
        const int   ok = __shfl_xor(best_k, 32);
        if (od < best_d || (od == best_d && ok < best_k)) {
            best_d = od; best_k = ok;
        }
    }

    // epilogue: lanes 0..31 own positions
    if (tid < POSB) {
        const int n = n0 + tid;
        out[IDX_OFF + (size_t)n] = (float)best_k;

        const float4* q4 = (const float4*)(cb + (size_t)best_k * CDIM);
        float* op = out + (size_t)b * CDIM * HWSZ + hw0 + tid;
        #pragma unroll
        for (int q = 0; q < CDIM / 4; ++q) {
            const float4 v = q4[q];
            op[(size_t)(4 * q + 0) * HWSZ] = v.x;
            op[(size_t)(4 * q + 1) * HWSZ] = v.y;
            op[(size_t)(4 * q + 2) * HWSZ] = v.z;
            op[(size_t)(4 * q + 3) * HWSZ] = v.w;
        }
        // packed u16 histogram (max 32/block per code, no overflow)
        atomicAdd(&lhist2[best_k >> 1], 1u << (16 * (best_k & 1)));
    }

    // loss: sum best_d over the 32 positions (upper half contributes 0)
    float sum = (tid < POSB) ? best_d : 0.0f;
    #pragma unroll
    for (int m = 1; m < 64; m <<= 1) sum += __shfl_xor(sum, m);
    if (tid == 0) atomicAdd(&ws[WS_LOSS], sum);
    __syncthreads();

    unsigned int* ghist = (unsigned int*)ws + WS_HIST;
    for (int i = tid; i < KCODES / 2; i += 64) {
        const unsigned int v = lhist2[i];
        if (v & 0xffffu) atomicAdd(&ghist[2 * i],     v & 0xffffu);
        if (v >> 16)     atomicAdd(&ghist[2 * i + 1], v >> 16);
    }
}

// ---- pass 2: scalars --------------------------------------------------------
__global__ __launch_bounds__(1024) void vq_final(const float* __restrict__ ws,
                                                 float* __restrict__ out) {
    __shared__ float red[1024];
    const int t = threadIdx.x;
    const unsigned int* hist = (const unsigned int*)ws + WS_HIST;
    const float p = (float)hist[t] * INV_NPOS;
    red[t] = p * logf(p + 1e-10f);
    __syncthreads();
    for (int s = 512; s > 0; s >>= 1) {
        if (t < s) red[t] += red[t + s];
        __syncthreads();
    }
    if (t == 0) {
        out[LOSS_OFF] = 1.25f * (ws[WS_LOSS] * INV_TOTAL);   // cb + 0.25*commit
        out[PERP_OFF] = expf(-red[0]);
    }
}

extern "C" void kernel_launch(void* const* d_in, const int* in_sizes, int n_in,
                              void* d_out, int out_size, void* d_ws, size_t ws_size,
                              hipStream_t stream) {
    const float* z  = (const float*)d_in[0];
    const float* cb = (const float*)d_in[1];
    float* out = (float*)d_out;
    float* ws  = (float*)d_ws;

    vq_prep <<<KCODES / 256, 256, 0, stream>>>(cb, ws);
    vq_main <<<NPOS / POSB,   64, 0, stream>>>(z, cb, ws, out);
    vq_final<<<1,           1024, 0, stream>>>(ws, out);
}